// Round 10
// baseline (194.013 us; speedup 1.0000x reference)
//
#include <hip/hip_runtime.h>

typedef __attribute__((ext_vector_type(4))) int            vi4;
typedef __attribute__((ext_vector_type(4))) float          vf4;
typedef __attribute__((ext_vector_type(8))) short          vs8;
typedef __attribute__((ext_vector_type(4))) short          vs4;
typedef __attribute__((ext_vector_type(2))) unsigned int   vu2;
typedef unsigned short u16;
typedef unsigned int   u32;

#define LOG2E  1.4426950408889634f
#define QSCALE 0.2550484109f   /* (1/sqrt(32)) * log2(e) */

static __device__ __forceinline__ u16 f2bf(float f) {
  u32 u = __builtin_bit_cast(u32, f);
  u32 r = (u + 0x7fffu + ((u >> 16) & 1u)) >> 16;   // RNE
  return (u16)r;
}
static __device__ __forceinline__ float bfu_lo(u32 u) {
  return __builtin_bit_cast(float, u << 16);
}
static __device__ __forceinline__ float bfu_hi(u32 u) {
  return __builtin_bit_cast(float, u & 0xffff0000u);
}
// pack bf16(trunc) of a (lo) and b (hi) in one v_perm_b32
static __device__ __forceinline__ u32 packbf_perm(float a, float b) {
  return __builtin_amdgcn_perm(__builtin_bit_cast(u32, b),
                               __builtin_bit_cast(u32, a), 0x07060302u);
}
static __device__ __forceinline__ vf4 unpack_bias(const u32* grp, int tj) {
  u32 b0 = grp[tj * 2], b1 = grp[tj * 2 + 1];
  vf4 c; c[0] = bfu_lo(b0); c[1] = bfu_hi(b0);
  c[2] = bfu_lo(b1); c[3] = bfu_hi(b1);
  return c;
}
// pack 8 fp32 -> 4 u32 of bf16 pairs (RNE)
static __device__ __forceinline__ vi4 cvt8(vf4 a, vf4 b) {
  vi4 o;
  o[0] = (int)((u32)f2bf(a[0]) | ((u32)f2bf(a[1]) << 16));
  o[1] = (int)((u32)f2bf(a[2]) | ((u32)f2bf(a[3]) << 16));
  o[2] = (int)((u32)f2bf(b[0]) | ((u32)f2bf(b[1]) << 16));
  o[3] = (int)((u32)f2bf(b[2]) | ((u32)f2bf(b[3]) << 16));
  return o;
}
// raw v_exp_f32: args are bounded (|x| small); x < -126 flushes to 0 which is
// exactly right for softmax. Avoids the ~6-instr denormal-safe libm expansion.
static __device__ __forceinline__ float exp2_raw(float x) {
#if __has_builtin(__builtin_amdgcn_exp2f)
  return __builtin_amdgcn_exp2f(x);
#else
  float r;
  asm("v_exp_f32 %0, %1" : "=v"(r) : "v"(x));
  return r;
#endif
}

// async global->LDS DMA, 16B per lane. LDS dest = wave-uniform base + lane*16.
static __device__ __forceinline__ void ldsdma16(void* lds, const void* g) {
  __builtin_amdgcn_global_load_lds(
      (const u32 __attribute__((address_space(1)))*)g,
      (u32 __attribute__((address_space(3)))*)lds, 16, 0, 0);
}

// ---------------- weight transpose prep ----------------
// [0,768) Wqkv^T | [768,1024) Wout^T
__global__ void prep_w(const float* __restrict__ Wqkv, u16* __restrict__ WqkvT,
                       const float* __restrict__ Wout, u16* __restrict__ WoutT) {
  int bid = blockIdx.x, tid = threadIdx.x;
  const float* src; u16* dst; int C, idx;
  if (bid < 768) { src = Wqkv; dst = WqkvT; C = 768; idx = bid * 256 + tid; }
  else           { src = Wout; dst = WoutT; C = 256; idx = (bid - 768) * 256 + tid; }
  int r = idx / C, c = idx - r * C;
  dst[c * 256 + r] = f2bf(src[idx]);
}

// ---------------- GEMM0 + bias prep (one launch) ----------------
// bid < 1536: QKV = x(fp32, converted in-staging) * WqkvT^T, 128x128 tiles.
//   XCD-bijective: m-tile = (bid&7)*32 + (bid>>3)&31, n = bid>>8.
//   A: reg-staged (global fp32 -> f2bf -> ds_write), B: global_load_lds DMA.
//   Per step outstanding at publish = B(k)2 + Aloads(k+1)4 + B(k+1)2 = 8
//   -> vmcnt(6) retires exactly B(k); lgkmcnt(0) covers A ds_writes.
// bid >= 1536: bias table gather (independent of gemm inputs; overlaps).
__global__ __launch_bounds__(256, 4) void gemm_qkv_bias(
    const float* __restrict__ x, const u16* __restrict__ Bt,
    u16* __restrict__ q_out, u16* __restrict__ k_out, u16* __restrict__ v_out,
    const int* __restrict__ rel, const float* __restrict__ table,
    u32* __restrict__ bias_pk) {
  __shared__ __align__(16) u16 SMEM[128 * 136];
  const int tid = threadIdx.x;
  const int bid = blockIdx.x;

  if (bid >= 1536) {
    // ---- bias path (b2 in [0,512)) ----
    int b2 = bid - 1536;
    int qt = b2 >> 6, t = (b2 >> 2) & 15, s = b2 & 3;
    int ti = s >> 1, jhalf = s & 1;
    int wave = tid >> 6, quad = (tid >> 4) & 3, l15 = tid & 15;
    int jbase = t * 64 + jhalf * 32;
    u16* relS = SMEM;

#pragma unroll
    for (int p = 0; p < 2; ++p) {
      int task = p * 256 + tid;                // 0..511
      int q = task >> 3, unit = task & 7;      // 64 rows x 8 vi4-units
      int m = qt * 128 + (q >> 4) * 32 + ti * 16 + (q & 15);
      vi4 v = *(const vi4*)&rel[m * 1024 + jbase + unit * 4];
      vu2 pk;
      pk[0] = (u32)(v[0] & 0xffff) | ((u32)v[1] << 16);
      pk[1] = (u32)(v[2] & 0xffff) | ((u32)v[3] << 16);
      *(vu2*)&relS[q * 32 + unit * 4] = pk;
    }
    __syncthreads();

    int mrow = wave * 16 + l15;
    float vals[8][8];                          // [tjl*4+r][h]
#pragma unroll
    for (int tjl = 0; tjl < 2; ++tjl)
#pragma unroll
      for (int r = 0; r < 4; ++r) {
        int idx = relS[mrow * 32 + tjl * 16 + quad * 4 + r];
        vf4 a = *(const vf4*)&table[idx * 8];
        vf4 bb = *(const vf4*)&table[idx * 8 + 4];
#pragma unroll
        for (int h = 0; h < 4; ++h) {
          vals[tjl * 4 + r][h] = a[h];
          vals[tjl * 4 + r][h + 4] = bb[h];
        }
      }
#pragma unroll
    for (int h = 0; h < 8; ++h) {
      u32 o[4];
#pragma unroll
      for (int tjl = 0; tjl < 2; ++tjl)
#pragma unroll
        for (int p = 0; p < 2; ++p) {
          u32 lo = f2bf(vals[tjl * 4 + 2 * p][h] * LOG2E);
          u32 hi = f2bf(vals[tjl * 4 + 2 * p + 1][h] * LOG2E);
          o[tjl * 2 + p] = lo | (hi << 16);
        }
      *(vi4*)&bias_pk[h * 524288 + (qt * 16 + t) * 4096 + s * 1024 + tid * 4] =
          *(const vi4*)o;
    }
    return;
  }

  // ---- gemm path ----
  const int lane15 = tid & 15, quad = (tid >> 4) & 3, wave = tid >> 6;
  const int wr = (wave & 1) * 64, wc = (wave >> 1) * 64;
  const int w = bid >> 3;
  const int m0 = (((bid & 7) << 5) + (w & 31)) * 128;
  const int n0 = (w >> 5) * 128;

  const float* Ax = &x[(m0 + (tid >> 2)) * 256 + (tid & 3) * 8];
  const u16* Bg = &Bt[(n0 + (tid >> 2)) * 256 + (tid & 3) * 8];
  // buf0: A [0,4096) B [4096,8192); buf1: A [8192,12288) B [12288,16384)
  u16* AsD0 = &SMEM[tid * 8];
  u16* AsD1 = &SMEM[8192 + tid * 8];
  u16* BsW0 = &SMEM[4096 + wave * 512];
  u16* BsW1 = &SMEM[12288 + wave * 512];

  const vf4 z4 = {0.f, 0.f, 0.f, 0.f};
  vf4 acc[4][4];
#pragma unroll
  for (int i = 0; i < 4; ++i)
#pragma unroll
    for (int j = 0; j < 4; ++j) acc[i][j] = z4;

  // prologue: stage k=0 into buf0 (A via regs+convert, B via DMA)
  {
    vf4 p0 = *(const vf4*)Ax;
    vf4 p1 = *(const vf4*)(Ax + 4);
    vf4 p2 = *(const vf4*)(Ax + 64 * 256);
    vf4 p3 = *(const vf4*)(Ax + 64 * 256 + 4);
    ldsdma16(BsW0,        Bg);
    ldsdma16(BsW0 + 2048, Bg + 64 * 256);
    *(vi4*)AsD0 = cvt8(p0, p1);
    *(vi4*)(AsD0 + 2048) = cvt8(p2, p3);
  }

#define GQ_TILE(KS, CUR)                                                       \
  do {                                                                         \
    vf4 a0, a1, a2, a3;                                                        \
    if ((KS) < 7) {                                                            \
      const float* ax = Ax + ((KS) + 1) * 32;                                  \
      a0 = *(const vf4*)ax;                                                    \
      a1 = *(const vf4*)(ax + 4);                                              \
      a2 = *(const vf4*)(ax + 64 * 256);                                       \
      a3 = *(const vf4*)(ax + 64 * 256 + 4);                                   \
      u16* db = (CUR) ? BsW0 : BsW1;                                           \
      ldsdma16(db,        Bg + ((KS) + 1) * 32);                               \
      ldsdma16(db + 2048, Bg + ((KS) + 1) * 32 + 64 * 256);                    \
      __builtin_amdgcn_sched_barrier(0);                                       \
      asm volatile("s_waitcnt vmcnt(6)" ::: "memory");                         \
    } else {                                                                   \
      asm volatile("s_waitcnt vmcnt(0)" ::: "memory");                         \
    }                                                                          \
    asm volatile("s_waitcnt lgkmcnt(0)" ::: "memory");                         \
    __builtin_amdgcn_sched_barrier(0);                                         \
    __builtin_amdgcn_s_barrier();       /* publish buf[CUR] */                 \
    __builtin_amdgcn_sched_barrier(0);                                         \
    {                                                                          \
      const u16* Ab = (CUR) ? &SMEM[8192] : &SMEM[0];                          \
      const u16* Bb = Ab + 4096;                                               \
      vs8 af[4], bfr[4];                                                       \
      _Pragma("unroll")                                                        \
      for (int ti = 0; ti < 4; ++ti)                                           \
        af[ti] = *(const vs8*)&Ab[(wr + ti * 16 + lane15) * 32 + quad * 8];    \
      _Pragma("unroll")                                                        \
      for (int tj = 0; tj < 4; ++tj)                                           \
        bfr[tj] = *(const vs8*)&Bb[(wc + tj * 16 + lane15) * 32 + quad * 8];   \
      _Pragma("unroll")                                                        \
      for (int ti = 0; ti < 4; ++ti)                                           \
        _Pragma("unroll")                                                      \
        for (int tj = 0; tj < 4; ++tj)                                         \
          acc[ti][tj] = __builtin_amdgcn_mfma_f32_16x16x32_bf16(               \
              af[ti], bfr[tj], acc[ti][tj], 0, 0, 0);                          \
    }                                                                          \
    __builtin_amdgcn_sched_barrier(0);                                         \
    if ((KS) < 7) {                                                            \
      u16* ad = (CUR) ? AsD0 : AsD1;   /* write the OTHER buffer */            \
      *(vi4*)ad = cvt8(a0, a1);                                                \
      *(vi4*)(ad + 2048) = cvt8(a2, a3);                                       \
    }                                                                          \
    __builtin_amdgcn_sched_barrier(0);                                         \
    __builtin_amdgcn_s_barrier();       /* reads done before next overwrite */ \
  } while (0)

#pragma unroll
  for (int kk = 0; kk < 8; kk += 2) {
    GQ_TILE(kk, 0);
    GQ_TILE(kk + 1, 1);
  }
#undef GQ_TILE

  const int which = n0 >> 8;
  const int bb = m0 >> 10, nn0 = m0 & 1023;
  u16* Cs = SMEM;                               // [128][136]
  __syncthreads();                              // As/Bs reads done
  if (which < 2) {
    float sc = (which == 0) ? QSCALE : 1.f;
#pragma unroll
    for (int tj = 0; tj < 4; ++tj) {
      int col = wc + tj * 16 + lane15;
#pragma unroll
      for (int ti = 0; ti < 4; ++ti) {
        int row0 = wr + ti * 16 + quad * 4;
#pragma unroll
        for (int r = 0; r < 4; ++r)
          Cs[(row0 + r) * 136 + col] = f2bf(acc[ti][tj][r] * sc);
      }
    }
    __syncthreads();
    u16* base = (which == 0) ? q_out : k_out;
#pragma unroll
    for (int hp = 0; hp < 4; ++hp) {
      int hh = ((n0 + hp * 32) >> 5) & 7;
      u16* pb = base + ((bb * 8 + hh) * 1024 + nn0) * 32;
#pragma unroll
      for (int p2 = 0; p2 < 2; ++p2) {
        int task = p2 * 256 + tid;
        int row = task >> 2, unit = task & 3;
        vi4 v = *(const vi4*)&Cs[row * 136 + hp * 32 + unit * 8];
        *(vi4*)&pb[row * 32 + unit * 8] = v;
      }
    }
  } else {
    // V: stage transposed -> [bh][d][n] contiguous stores
#pragma unroll
    for (int tj = 0; tj < 4; ++tj) {
      int col = wc + tj * 16 + lane15;
#pragma unroll
      for (int ti = 0; ti < 4; ++ti) {
        int row0 = wr + ti * 16 + quad * 4;
        vu2 pk;
        pk[0] = (u32)f2bf(acc[ti][tj][0]) | ((u32)f2bf(acc[ti][tj][1]) << 16);
        pk[1] = (u32)f2bf(acc[ti][tj][2]) | ((u32)f2bf(acc[ti][tj][3]) << 16);
        *(vu2*)&Cs[col * 136 + row0] = pk;
      }
    }
    __syncthreads();
#pragma unroll
    for (int p = 0; p < 8; ++p) {
      int task = p * 256 + tid;
      int col = task >> 4, unit = task & 15;
      int cg = n0 + col;
      int hh = (cg >> 5) & 7, d = cg & 31;
      vi4 v = *(const vi4*)&Cs[col * 136 + unit * 8];
      *(vi4*)&v_out[((bb * 8 + hh) * 32 + d) * 1024 + nn0 + unit * 8] = v;
    }
  }
}

// ---------------- GEMM1: out = O * WoutT^T + b  (64x128 tiles) ----------------
__global__ __launch_bounds__(256, 4) void gemm_out(
    const u16* __restrict__ A, const u16* __restrict__ Bt,
    float* __restrict__ c_out, const float* __restrict__ bias) {
  __shared__ __align__(16) u16 SMEM[12288];   // 2 bufs x (2048 A + 4096 B)
  const int tid = threadIdx.x;
  const int lane15 = tid & 15, quad = (tid >> 4) & 3, wave = tid >> 6;
  const int bid = blockIdx.x;
  const int mt = ((bid & 7) << 6) + ((bid >> 3) & 63);   // XCD-bijective
  const int m0 = mt * 64;
  const int n0 = (bid >> 9) << 7;

  const u16* Ag = &A[(m0 + (tid >> 2)) * 256 + (tid & 3) * 8];
  const u16* Bg = &Bt[(n0 + (tid >> 2)) * 256 + (tid & 3) * 8];
  u16* AsW0 = &SMEM[wave * 512];
  u16* BsW0 = &SMEM[2048 + wave * 512];
  u16* AsW1 = &SMEM[6144 + wave * 512];
  u16* BsW1 = &SMEM[8192 + wave * 512];

  const vf4 z4 = {0.f, 0.f, 0.f, 0.f};
  vf4 acc[4][2];
#pragma unroll
  for (int i = 0; i < 4; ++i) {
    acc[i][0] = z4; acc[i][1] = z4;
  }

  // prologue: stage k=0 into buf0
  ldsdma16(AsW0,        Ag);
  ldsdma16(BsW0,        Bg);
  ldsdma16(BsW0 + 2048, Bg + 64 * 256);

#define GO_TILE(KS, CUR)                                                       \
  do {                                                                         \
    if ((KS) < 7) {                                                            \
      u16* da = (CUR) ? AsW0 : AsW1;                                           \
      u16* db = (CUR) ? BsW0 : BsW1;                                           \
      ldsdma16(da,        Ag + ((KS) + 1) * 32);                               \
      ldsdma16(db,        Bg + ((KS) + 1) * 32);                               \
      ldsdma16(db + 2048, Bg + ((KS) + 1) * 32 + 64 * 256);                    \
      asm volatile("s_waitcnt vmcnt(3)" ::: "memory");                         \
    } else {                                                                   \
      asm volatile("s_waitcnt vmcnt(0)" ::: "memory");                         \
    }                                                                          \
    __builtin_amdgcn_sched_barrier(0);                                         \
    __builtin_amdgcn_s_barrier();                                              \
    __builtin_amdgcn_sched_barrier(0);                                         \
    {                                                                          \
      const u16* Ab = (CUR) ? &SMEM[6144] : &SMEM[0];                          \
      const u16* Bb = Ab + 2048;                                               \
      vs8 af[4], bfr[2];                                                       \
      _Pragma("unroll")                                                        \
      for (int ti = 0; ti < 4; ++ti)                                           \
        af[ti] = *(const vs8*)&Ab[(ti * 16 + lane15) * 32 + quad * 8];         \
      _Pragma("unroll")                                                        \
      for (int tj = 0; tj < 2; ++tj)                                           \
        bfr[tj] = *(const vs8*)&Bb[(wave * 32 + tj * 16 + lane15) * 32         \
                                   + quad * 8];                                \
      _Pragma("unroll")                                                        \
      for (int ti = 0; ti < 4; ++ti)                                           \
        _Pragma("unroll")                                                      \
        for (int tj = 0; tj < 2; ++tj)                                         \
          acc[ti][tj] = __builtin_amdgcn_mfma_f32_16x16x32_bf16(               \
              af[ti], bfr[tj], acc[ti][tj], 0, 0, 0);                          \
    }                                                                          \
    __builtin_amdgcn_sched_barrier(0);                                         \
    __builtin_amdgcn_s_barrier();                                              \
  } while (0)

#pragma unroll
  for (int kk = 0; kk < 8; kk += 2) {
    GO_TILE(kk, 0);
    GO_TILE(kk + 1, 1);
  }
#undef GO_TILE

#pragma unroll
  for (int tj = 0; tj < 2; ++tj) {
    int colg = n0 + wave * 32 + tj * 16 + lane15;
    float bo = bias[colg];
#pragma unroll
    for (int ti = 0; ti < 4; ++ti)
#pragma unroll
      for (int r = 0; r < 4; ++r) {
        int rowg = m0 + ti * 16 + quad * 4 + r;
        c_out[rowg * 256 + colg] = acc[ti][tj][r] + bo;
      }
  }
}

// ---------------- flash attention (S^T, K=16 PV: P feeds MFMA in-register) ----
// S^T frag layout (mfma 16x16x32, A=K, B=Q):  P[j = quad*4+r][m = l15].
// B-operand layout of mfma 16x16x16:          B[k = quad*4+i][n = l15].
// => identical: exp2'd P packs straight into the PV B-operand. No P LDS.
// Tile loop unrolled by 2 so the LDS double-buffer index is compile-time.
// NOTE: (256, 4) launch bounds — (256, 8) caps unified VGPR+AGPR at 64/lane
// and spills everything to scratch (measured: 2.1 GB HBM traffic, 4.4x slower).
template <int BF32>
__global__ __launch_bounds__(256, 4) void flash_attn(
    const u16* __restrict__ Qws, const u16* __restrict__ Kws,
    const u16* __restrict__ Vtws, const void* __restrict__ biasv,
    u16* __restrict__ Ows) {
  __shared__ __align__(16) u16 Ks[2][64 * 40];   // double-buffered K
  __shared__ __align__(16) u16 Vt[2][32 * 72];   // double-buffered V^T

  const int tid = threadIdx.x;
  const int l15 = tid & 15, quad = (tid >> 4) & 3, wave = tid >> 6;
  const int bid = blockIdx.x;
  const int h = bid & 7, b = (bid >> 3) & 31, qt = bid >> 8;
  const int q0 = qt * 128;
  const int bh = b * 8 + h;
  const u16* Qbase = Qws + (bh * 1024 + q0) * 32;
  const u16* Kbase = Kws + bh * 1024 * 32;
  const u16* Vbase = Vtws + bh * 32 * 1024;
  const float* Bf = (const float*)biasv + (h * 8 + qt) * 131072 + tid * 4;
  const u32*  Bpk = (const u32*)biasv + h * 524288 + qt * 65536 + tid * 4;

  const int kv_j = tid >> 2, kv_seg = (tid & 3) * 8;
  const int v_d = tid >> 3,  v_seg = (tid & 7) * 8;
  const u16* Kg = Kbase + kv_j * 32 + kv_seg;
  const u16* Vg = Vbase + v_d * 1024 + v_seg;

  // Q fragments straight from global (one-time, 2x 16B/lane)
  vs8 af[2];
#pragma unroll
  for (int ti = 0; ti < 2; ++ti)
    af[ti] = *(const vs8*)&Qbase[(wave * 32 + ti * 16 + l15) * 32 + quad * 8];

  // prologue: tile 0 into LDS buf 0
  vi4 kreg = *(const vi4*)Kg;
  vi4 vreg = *(const vi4*)Vg;
  *(vi4*)&Ks[0][kv_j * 40 + kv_seg] = kreg;
  *(vi4*)&Vt[0][v_d * 72 + v_seg] = vreg;

  // bias prefetch for ti=0 fragments of t=0 (s-major layout: s*1024 + tid*4)
  vf4 b0pre[4];
  vi4 bpk_pre[2];
  if (BF32) {
#pragma unroll
    for (int i = 0; i < 4; ++i) b0pre[i] = *(const vf4*)&Bf[i * 1024];
  } else {
#pragma unroll
    for (int i = 0; i < 2; ++i) bpk_pre[i] = *(const vi4*)(Bpk + i * 1024);
  }

  const vf4 z4 = {0.f, 0.f, 0.f, 0.f};
  vf4 O[2][2];
  O[0][0] = z4; O[0][1] = z4; O[1][0] = z4; O[1][1] = z4;
  vf4 Lacc[2];
  Lacc[0] = z4; Lacc[1] = z4;

  vs4 ones4;
#pragma unroll
  for (int i = 0; i < 4; ++i) ones4[i] = (short)0x3F80;   // bf16 1.0

  const int ks_off = l15 * 40 + quad * 8;        // + tj*640
  const int vt_off = l15 * 72 + quad * 4;        // + tj2*1152 + tj*16

#define FA_TILE(T, CUR)                                                        \
  do {                                                                         \
    __syncthreads(); /* buf[CUR] (written last iter) visible */                \
    /* bias for ti=1 frags of this tile -- issued FIRST so its waitcnt */      \
    /* leaves the next-tile K/V loads in flight */                             \
    vf4 b1cur[4];                                                              \
    vi4 bpk1[2];                                                               \
    if (BF32) {                                                                \
      _Pragma("unroll")                                                        \
      for (int i = 0; i < 4; ++i)                                              \
        b1cur[i] = *(const vf4*)&Bf[((T) * 8 + 4 + i) * 1024];                 \
    } else {                                                                   \
      bpk1[0] = *(const vi4*)(Bpk + (T) * 4096 + 2048);                        \
      bpk1[1] = *(const vi4*)(Bpk + (T) * 4096 + 3072);                        \
    }                                                                          \
    if ((T) < 15) {                                                            \
      kreg = *(const vi4*)(Kg + ((T) + 1) * 2048);                             \
      vreg = *(const vi4*)(Vg + ((T) + 1) * 64);                               \
    }                                                                          \
    __builtin_amdgcn_s_setprio(1);                                             \
    _Pragma("unroll")                                                          \
    for (int tj = 0; tj < 4; ++tj) {                                           \
      vs8 bk = *(const vs8*)&Ks[CUR][tj * 640 + ks_off];                       \
      vs4 va0 = *(const vs4*)&Vt[CUR][vt_off + tj * 16];                       \
      vs4 va1 = *(const vs4*)&Vt[CUR][vt_off + 1152 + tj * 16];                \
      _Pragma("unroll")                                                        \
      for (int ti = 0; ti < 2; ++ti) {                                         \
        vf4 c = BF32 ? (ti ? b1cur[tj] : b0pre[tj])                            \
                     : unpack_bias((const u32*)(ti ? bpk1 : bpk_pre), tj);     \
        vf4 st = __builtin_amdgcn_mfma_f32_16x16x32_bf16(bk, af[ti], c,        \
                                                         0, 0, 0);             \
        float p0 = exp2_raw(st[0]);                                            \
        float p1 = exp2_raw(st[1]);                                            \
        float p2 = exp2_raw(st[2]);                                            \
        float p3 = exp2_raw(st[3]);                                            \
        vu2 pw; pw[0] = packbf_perm(p0, p1); pw[1] = packbf_perm(p2, p3);      \
        vs4 pf = __builtin_bit_cast(vs4, pw);                                  \
        O[ti][0] = __builtin_amdgcn_mfma_f32_16x16x16bf16_1k(va0, pf,          \
                                                             O[ti][0], 0, 0, 0); \
        O[ti][1] = __builtin_amdgcn_mfma_f32_16x16x16bf16_1k(va1, pf,          \
                                                             O[ti][1], 0, 0, 0); \
        Lacc[ti] = __builtin_amdgcn_mfma_f32_16x16x16bf16_1k(ones4, pf,        \
                                                             Lacc[ti], 0, 0, 0); \
      }                                                                        \
    }                                                                          \
    __builtin_amdgcn_s_setprio(0);                                             \
    /* stage next tile into the other LDS buffer; roll ti=0 bias prefetch */   \
    if ((T) < 15) {                                                            \
      *(vi4*)&Ks[(CUR) ^ 1][kv_j * 40 + kv_seg] = kreg;                        \
      *(vi4*)&Vt[(CUR) ^ 1][v_d * 72 + v_seg] = vreg;                          \
      if (BF32) {                                                              \
        _Pragma("unroll")                                                      \
        for (int i = 0; i < 4; ++i)                                            \
          b0pre[i] = *(const vf4*)&Bf[(((T) + 1) * 8 + i) * 1024];             \
      } else {                                                                 \
        bpk_pre[0] = *(const vi4*)(Bpk + ((T) + 1) * 4096);                    \
        bpk_pre[1] = *(const vi4*)(Bpk + ((T) + 1) * 4096 + 1024);             \
      }                                                                        \
    }                                                                          \
  } while (0)

  for (int tt = 0; tt < 16; tt += 2) {
    FA_TILE(tt, 0);
    FA_TILE(tt + 1, 1);
  }
#undef FA_TILE

  // epilogue
#pragma unroll
  for (int ti = 0; ti < 2; ++ti) {
    float inv = __builtin_amdgcn_rcpf(Lacc[ti][0]);
    int m = q0 + wave * 32 + ti * 16 + l15;
    int rowbase = (b * 1024 + m) * 256 + h * 32;
#pragma unroll
    for (int tj2 = 0; tj2 < 2; ++tj2) {
      u32 lo = (u32)f2bf(O[ti][tj2][0] * inv) | ((u32)f2bf(O[ti][tj2][1] * inv) << 16);
      u32 hi = (u32)f2bf(O[ti][tj2][2] * inv) | ((u32)f2bf(O[ti][tj2][3] * inv) << 16);
      vu2 pk; pk[0] = lo; pk[1] = hi;
      *(vu2*)&Ows[rowbase + tj2 * 16 + quad * 4] = pk;
    }
  }
}

// ---------------- launch ----------------
extern "C" void kernel_launch(void* const* d_in, const int* in_sizes, int n_in,
                              void* d_out, int out_size, void* d_ws, size_t ws_size,
                              hipStream_t stream) {
  (void)in_sizes; (void)n_in; (void)out_size;
  const float* x     = (const float*)d_in[0];
  const float* Wqkv  = (const float*)d_in[1];
  const float* table = (const float*)d_in[2];
  const float* Wout  = (const float*)d_in[3];
  const float* bout  = (const float*)d_in[4];
  const int*   rel   = (const int*)d_in[5];
  float* out = (float*)d_out;

  const size_t bias_bytes = 16777216ull;

  char* ws = (char*)d_ws;
  u16* Ows    = (u16*)(ws);              // flash O output (bf16)
  u16* Qws    = (u16*)(ws + 16777216);
  u16* Kws    = (u16*)(ws + 33554432);
  u16* Vtws   = (u16*)(ws + 50331648);   // [32][8][32][1024] V^T
  void* biasp = (void*)(ws + 67108864);
  u16* WqkvT  = (u16*)(ws + 67108864 + bias_bytes);
  u16* WoutT  = WqkvT + 196608;

  prep_w<<<1024, 256, 0, stream>>>(Wqkv, WqkvT, Wout, WoutT);
  gemm_qkv_bias<<<2048, 256, 0, stream>>>(x, WqkvT, Qws, Kws, Vtws,
                                          rel, table, (u32*)biasp);
  flash_attn<0><<<2048, 256, 0, stream>>>(Qws, Kws, Vtws, biasp, Ows);
  gemm_out<<<1024, 256, 0, stream>>>(Ows, WoutT, out, bout);
}

// Round 11
// 184.784 us; speedup vs baseline: 1.0499x; 1.0499x over previous
//
#include <hip/hip_runtime.h>

typedef __attribute__((ext_vector_type(4))) int            vi4;
typedef __attribute__((ext_vector_type(4))) float          vf4;
typedef __attribute__((ext_vector_type(8))) short          vs8;
typedef __attribute__((ext_vector_type(4))) short          vs4;
typedef __attribute__((ext_vector_type(2))) unsigned int   vu2;
typedef unsigned short u16;
typedef unsigned int   u32;

#define LOG2E  1.4426950408889634f
#define QSCALE 0.2550484109f   /* (1/sqrt(32)) * log2(e) */

static __device__ __forceinline__ u16 f2bf(float f) {
  u32 u = __builtin_bit_cast(u32, f);
  u32 r = (u + 0x7fffu + ((u >> 16) & 1u)) >> 16;   // RNE
  return (u16)r;
}
static __device__ __forceinline__ float bfu_lo(u32 u) {
  return __builtin_bit_cast(float, u << 16);
}
static __device__ __forceinline__ float bfu_hi(u32 u) {
  return __builtin_bit_cast(float, u & 0xffff0000u);
}
// pack bf16(trunc) of a (lo) and b (hi) in one v_perm_b32
static __device__ __forceinline__ u32 packbf_perm(float a, float b) {
  return __builtin_amdgcn_perm(__builtin_bit_cast(u32, b),
                               __builtin_bit_cast(u32, a), 0x07060302u);
}
static __device__ __forceinline__ vf4 unpack_bias(const u32* grp, int tj) {
  u32 b0 = grp[tj * 2], b1 = grp[tj * 2 + 1];
  vf4 c; c[0] = bfu_lo(b0); c[1] = bfu_hi(b0);
  c[2] = bfu_lo(b1); c[3] = bfu_hi(b1);
  return c;
}
// raw v_exp_f32: args are bounded (|x| small); x < -126 flushes to 0 which is
// exactly right for softmax. Avoids the ~6-instr denormal-safe libm expansion.
static __device__ __forceinline__ float exp2_raw(float x) {
#if __has_builtin(__builtin_amdgcn_exp2f)
  return __builtin_amdgcn_exp2f(x);
#else
  float r;
  asm("v_exp_f32 %0, %1" : "=v"(r) : "v"(x));
  return r;
#endif
}

// async global->LDS DMA, 16B per lane. LDS dest = wave-uniform base + lane*16.
static __device__ __forceinline__ void ldsdma16(void* lds, const void* g) {
  __builtin_amdgcn_global_load_lds(
      (const u32 __attribute__((address_space(1)))*)g,
      (u32 __attribute__((address_space(3)))*)lds, 16, 0, 0);
}

// ---------------- fused prep ----------------
// grid: [0,4096) cvt x (8 f/thread) | [4096,4864) Wqkv^T | [4864,5120) Wout^T
//       | [5120,5632) bias
// Bias in S^T MFMA C-fragment order (score col m = l15, row j = quad*4+r).
//   bf16 packed (s-major, full-line stores):
//     u32 idx = h*524288 + (qt*16+t)*4096 + s*1024 + tid*4 + (tjl*2+p)
__global__ void prep_all(const float* __restrict__ x, u16* __restrict__ xbf,
                         const float* __restrict__ Wqkv, u16* __restrict__ WqkvT,
                         const float* __restrict__ Wout, u16* __restrict__ WoutT,
                         const int* __restrict__ rel, const float* __restrict__ table,
                         u32* __restrict__ bias_pk, float* __restrict__ bias_f,
                         int use_f32) {
  __shared__ __align__(8) u16 relS[64 * 32];
  int bid = blockIdx.x, tid = threadIdx.x;
  if (bid < 4096) {
    int i = (bid * 256 + tid) * 8;
    vf4 v0 = *(const vf4*)&x[i];
    vf4 v1 = *(const vf4*)&x[i + 4];
    vi4 o;
    o[0] = (int)((u32)f2bf(v0[0]) | ((u32)f2bf(v0[1]) << 16));
    o[1] = (int)((u32)f2bf(v0[2]) | ((u32)f2bf(v0[3]) << 16));
    o[2] = (int)((u32)f2bf(v1[0]) | ((u32)f2bf(v1[1]) << 16));
    o[3] = (int)((u32)f2bf(v1[2]) | ((u32)f2bf(v1[3]) << 16));
    *(vi4*)&xbf[i] = o;
  } else if (bid < 5120) {
    const float* src; u16* dst; int C, idx;
    if (bid < 4864) { src = Wqkv; dst = WqkvT; C = 768; idx = (bid - 4096) * 256 + tid; }
    else            { src = Wout; dst = WoutT; C = 256; idx = (bid - 4864) * 256 + tid; }
    int r = idx / C, c = idx - r * C;
    dst[c * 256 + r] = f2bf(src[idx]);
  } else {
    int b2 = bid - 5120;                       // 0..511
    int qt = b2 >> 6, t = (b2 >> 2) & 15, s = b2 & 3;
    int ti = s >> 1, jhalf = s & 1;
    int wave = tid >> 6, quad = (tid >> 4) & 3, l15 = tid & 15;
    int jbase = t * 64 + jhalf * 32;

    // phase 1: coalesced rel tile -> LDS (u16). LDS row q -> m, 32 j per row.
#pragma unroll
    for (int p = 0; p < 2; ++p) {
      int task = p * 256 + tid;                // 0..511
      int q = task >> 3, unit = task & 7;      // 64 rows x 8 vi4-units
      int m = qt * 128 + (q >> 4) * 32 + ti * 16 + (q & 15);
      vi4 v = *(const vi4*)&rel[m * 1024 + jbase + unit * 4];
      vu2 pk;
      pk[0] = (u32)(v[0] & 0xffff) | ((u32)v[1] << 16);
      pk[1] = (u32)(v[2] & 0xffff) | ((u32)v[3] << 16);
      *(vu2*)&relS[q * 32 + unit * 4] = pk;
    }
    __syncthreads();

    // phase 2: gather table, emit fragments
    int mrow = wave * 16 + l15;
    float vals[8][8];                          // [tjl*4+r][h]
#pragma unroll
    for (int tjl = 0; tjl < 2; ++tjl)
#pragma unroll
      for (int r = 0; r < 4; ++r) {
        int idx = relS[mrow * 32 + tjl * 16 + quad * 4 + r];
        vf4 a = *(const vf4*)&table[idx * 8];
        vf4 bb = *(const vf4*)&table[idx * 8 + 4];
#pragma unroll
        for (int h = 0; h < 4; ++h) {
          vals[tjl * 4 + r][h] = a[h];
          vals[tjl * 4 + r][h + 4] = bb[h];
        }
      }
    if (use_f32) {
#pragma unroll
      for (int h = 0; h < 8; ++h)
#pragma unroll
        for (int tjl = 0; tjl < 2; ++tjl) {
          int frag = ti * 4 + jhalf * 2 + tjl;
          vf4 v;
#pragma unroll
          for (int r = 0; r < 4; ++r) v[r] = vals[tjl * 4 + r][h] * LOG2E;
          *(vf4*)&bias_f[(((h * 8 + qt) * 16 + t) * 8 + frag) * 1024 + tid * 4] = v;
        }
    } else {
#pragma unroll
      for (int h = 0; h < 8; ++h) {
        u32 o[4];
#pragma unroll
        for (int tjl = 0; tjl < 2; ++tjl)
#pragma unroll
          for (int p = 0; p < 2; ++p) {
            u32 lo = f2bf(vals[tjl * 4 + 2 * p][h] * LOG2E);
            u32 hi = f2bf(vals[tjl * 4 + 2 * p + 1][h] * LOG2E);
            o[tjl * 2 + p] = lo | (hi << 16);
          }
        *(vi4*)&bias_pk[h * 524288 + (qt * 16 + t) * 4096 + s * 1024 + tid * 4] =
            *(const vi4*)o;
      }
    }
  }
}

// ---------------- GEMM: C[M x NC] = A[M x 256] * Bt[NC x 256]^T ----------------
// 1-D grid, XCD-bijective decode: m-tile = (bid&7)*32 + (bid>>3)&31, n = bid>>8.
// Each XCD owns a contiguous 2 MB A-panel -> A re-reads (6x / 2x) are L2 hits.
// K-loop: LDS double-buffer + counted s_waitcnt vmcnt(4) (not 0) so the 4
// next-tile DMAs stay in flight across the barrier (m201 pattern).
// launch_bounds (256,4): cap VGPR at 128 (live state ~120) -> 4 blocks/CU.
template <int EPI>
__global__ __launch_bounds__(256, 4) void gemm_k256(
    const u16* __restrict__ A, const u16* __restrict__ Bt,
    u16* __restrict__ q_out, u16* __restrict__ k_out, u16* __restrict__ v_out,
    float* __restrict__ c_out, const float* __restrict__ bias) {
  __shared__ __align__(16) u16 SMEM[EPI == 0 ? 128 * 136 : 16384];
  const int tid = threadIdx.x;
  const int lane15 = tid & 15, quad = (tid >> 4) & 3, wave = tid >> 6;
  const int wr = (wave & 1) * 64, wc = (wave >> 1) * 64;
  const int bid = blockIdx.x;
  const int w = bid >> 3;
  const int m0 = (((bid & 7) << 5) + (w & 31)) * 128;
  const int n0 = (w >> 5) * 128;

  const u16* Ag = &A[(m0 + (tid >> 2)) * 256 + (tid & 3) * 8];
  const u16* Bg = &Bt[(n0 + (tid >> 2)) * 256 + (tid & 3) * 8];
  // double buffer: buf0 = A@0, B@4096; buf1 = A@8192, B@12288 (u16 indices)
  u16* AsW0 = &SMEM[wave * 512];
  u16* BsW0 = &SMEM[4096 + wave * 512];
  u16* AsW1 = &SMEM[8192 + wave * 512];
  u16* BsW1 = &SMEM[12288 + wave * 512];

  const vf4 z4 = {0.f, 0.f, 0.f, 0.f};
  vf4 acc[4][4];
#pragma unroll
  for (int i = 0; i < 4; ++i)
#pragma unroll
    for (int j = 0; j < 4; ++j) acc[i][j] = z4;

  // prologue: stage k=0 into buf0
  ldsdma16(AsW0,        Ag);
  ldsdma16(AsW0 + 2048, Ag + 64 * 256);
  ldsdma16(BsW0,        Bg);
  ldsdma16(BsW0 + 2048, Bg + 64 * 256);

#define G_TILE(KS, CUR)                                                        \
  do {                                                                         \
    if ((KS) < 7) {                                                            \
      u16* da = (CUR) ? AsW0 : AsW1;   /* stage into the OTHER buffer */       \
      u16* db = (CUR) ? BsW0 : BsW1;                                           \
      ldsdma16(da,        Ag + ((KS) + 1) * 32);                               \
      ldsdma16(da + 2048, Ag + ((KS) + 1) * 32 + 64 * 256);                    \
      ldsdma16(db,        Bg + ((KS) + 1) * 32);                               \
      ldsdma16(db + 2048, Bg + ((KS) + 1) * 32 + 64 * 256);                    \
      asm volatile("s_waitcnt vmcnt(4)" ::: "memory");                         \
    } else {                                                                   \
      asm volatile("s_waitcnt vmcnt(0)" ::: "memory");                         \
    }                                                                          \
    __builtin_amdgcn_sched_barrier(0);                                         \
    __builtin_amdgcn_s_barrier();       /* buf[CUR] writes visible to all */   \
    __builtin_amdgcn_sched_barrier(0);                                         \
    {                                                                          \
      const u16* Ab = (CUR) ? &SMEM[8192] : &SMEM[0];                          \
      const u16* Bb = Ab + 4096;                                               \
      vs8 af[4], bfr[4];                                                       \
      _Pragma("unroll")                                                        \
      for (int ti = 0; ti < 4; ++ti)                                           \
        af[ti] = *(const vs8*)&Ab[(wr + ti * 16 + lane15) * 32 + quad * 8];    \
      _Pragma("unroll")                                                        \
      for (int tj = 0; tj < 4; ++tj)                                           \
        bfr[tj] = *(const vs8*)&Bb[(wc + tj * 16 + lane15) * 32 + quad * 8];   \
      _Pragma("unroll")                                                        \
      for (int ti = 0; ti < 4; ++ti)                                           \
        _Pragma("unroll")                                                      \
        for (int tj = 0; tj < 4; ++tj)                                         \
          acc[ti][tj] = __builtin_amdgcn_mfma_f32_16x16x32_bf16(               \
              af[ti], bfr[tj], acc[ti][tj], 0, 0, 0);                          \
    }                                                                          \
    __builtin_amdgcn_sched_barrier(0);                                         \
    __builtin_amdgcn_s_barrier();       /* reads done before next overwrite */ \
  } while (0)

#pragma unroll
  for (int kk = 0; kk < 8; kk += 2) {
    G_TILE(kk, 0);
    G_TILE(kk + 1, 1);
  }
#undef G_TILE

  if (EPI == 0) {
    const int which = n0 >> 8;
    const int bb = m0 >> 10, nn0 = m0 & 1023;
    u16* Cs = SMEM;                               // [128][136]
    __syncthreads();                              // As/Bs reads done
    if (which < 2) {
      float sc = (which == 0) ? QSCALE : 1.f;
#pragma unroll
      for (int tj = 0; tj < 4; ++tj) {
        int col = wc + tj * 16 + lane15;
#pragma unroll
        for (int ti = 0; ti < 4; ++ti) {
          int row0 = wr + ti * 16 + quad * 4;
#pragma unroll
          for (int r = 0; r < 4; ++r)
            Cs[(row0 + r) * 136 + col] = f2bf(acc[ti][tj][r] * sc);
        }
      }
      __syncthreads();
      u16* base = (which == 0) ? q_out : k_out;
#pragma unroll
      for (int hp = 0; hp < 4; ++hp) {
        int hh = ((n0 + hp * 32) >> 5) & 7;
        u16* pb = base + ((bb * 8 + hh) * 1024 + nn0) * 32;
#pragma unroll
        for (int p2 = 0; p2 < 2; ++p2) {
          int task = p2 * 256 + tid;
          int row = task >> 2, unit = task & 3;
          vi4 v = *(const vi4*)&Cs[row * 136 + hp * 32 + unit * 8];
          *(vi4*)&pb[row * 32 + unit * 8] = v;
        }
      }
    } else {
      // V: stage transposed -> [bh][d][n] contiguous stores
#pragma unroll
      for (int tj = 0; tj < 4; ++tj) {
        int col = wc + tj * 16 + lane15;
#pragma unroll
        for (int ti = 0; ti < 4; ++ti) {
          int row0 = wr + ti * 16 + quad * 4;
          vu2 pk;
          pk[0] = (u32)f2bf(acc[ti][tj][0]) | ((u32)f2bf(acc[ti][tj][1]) << 16);
          pk[1] = (u32)f2bf(acc[ti][tj][2]) | ((u32)f2bf(acc[ti][tj][3]) << 16);
          *(vu2*)&Cs[col * 136 + row0] = pk;
        }
      }
      __syncthreads();
#pragma unroll
      for (int p = 0; p < 8; ++p) {
        int task = p * 256 + tid;
        int col = task >> 4, unit = task & 15;
        int cg = n0 + col;
        int hh = (cg >> 5) & 7, d = cg & 31;
        vi4 v = *(const vi4*)&Cs[col * 136 + unit * 8];
        *(vi4*)&v_out[((bb * 8 + hh) * 32 + d) * 1024 + nn0 + unit * 8] = v;
      }
    }
  } else {
#pragma unroll
    for (int tj = 0; tj < 4; ++tj) {
      int colg = n0 + wc + tj * 16 + lane15;
      float bo = bias[colg];
#pragma unroll
      for (int ti = 0; ti < 4; ++ti)
#pragma unroll
        for (int r = 0; r < 4; ++r) {
          int rowg = m0 + wr + ti * 16 + quad * 4 + r;
          c_out[rowg * 256 + colg] = acc[ti][tj][r] + bo;
        }
    }
  }
}

// ---------------- flash attention (S^T, K=16 PV: P feeds MFMA in-register) ----
// S^T frag layout (mfma 16x16x32, A=K, B=Q):  P[j = quad*4+r][m = l15].
// B-operand layout of mfma 16x16x16:          B[k = quad*4+i][n = l15].
// => identical: exp2'd P packs straight into the PV B-operand. No P LDS.
// Tile loop unrolled by 2 so the LDS double-buffer index is compile-time.
// NOTE: (256, 4) launch bounds — (256, 8) caps unified VGPR+AGPR at 64/lane
// and spills everything to scratch (measured: 2.1 GB HBM traffic, 4.4x slower).
template <int BF32>
__global__ __launch_bounds__(256, 4) void flash_attn(
    const u16* __restrict__ Qws, const u16* __restrict__ Kws,
    const u16* __restrict__ Vtws, const void* __restrict__ biasv,
    u16* __restrict__ Ows) {
  __shared__ __align__(16) u16 Ks[2][64 * 40];   // double-buffered K
  __shared__ __align__(16) u16 Vt[2][32 * 72];   // double-buffered V^T

  const int tid = threadIdx.x;
  const int l15 = tid & 15, quad = (tid >> 4) & 3, wave = tid >> 6;
  const int bid = blockIdx.x;
  const int h = bid & 7, b = (bid >> 3) & 31, qt = bid >> 8;
  const int q0 = qt * 128;
  const int bh = b * 8 + h;
  const u16* Qbase = Qws + (bh * 1024 + q0) * 32;
  const u16* Kbase = Kws + bh * 1024 * 32;
  const u16* Vbase = Vtws + bh * 32 * 1024;
  const float* Bf = (const float*)biasv + (h * 8 + qt) * 131072 + tid * 4;
  const u32*  Bpk = (const u32*)biasv + h * 524288 + qt * 65536 + tid * 4;

  const int kv_j = tid >> 2, kv_seg = (tid & 3) * 8;
  const int v_d = tid >> 3,  v_seg = (tid & 7) * 8;
  const u16* Kg = Kbase + kv_j * 32 + kv_seg;
  const u16* Vg = Vbase + v_d * 1024 + v_seg;

  // Q fragments straight from global (one-time, 2x 16B/lane)
  vs8 af[2];
#pragma unroll
  for (int ti = 0; ti < 2; ++ti)
    af[ti] = *(const vs8*)&Qbase[(wave * 32 + ti * 16 + l15) * 32 + quad * 8];

  // prologue: tile 0 into LDS buf 0
  vi4 kreg = *(const vi4*)Kg;
  vi4 vreg = *(const vi4*)Vg;
  *(vi4*)&Ks[0][kv_j * 40 + kv_seg] = kreg;
  *(vi4*)&Vt[0][v_d * 72 + v_seg] = vreg;

  // bias prefetch for ti=0 fragments of t=0 (s-major layout: s*1024 + tid*4)
  vf4 b0pre[4];
  vi4 bpk_pre[2];
  if (BF32) {
#pragma unroll
    for (int i = 0; i < 4; ++i) b0pre[i] = *(const vf4*)&Bf[i * 1024];
  } else {
#pragma unroll
    for (int i = 0; i < 2; ++i) bpk_pre[i] = *(const vi4*)(Bpk + i * 1024);
  }

  const vf4 z4 = {0.f, 0.f, 0.f, 0.f};
  vf4 O[2][2];
  O[0][0] = z4; O[0][1] = z4; O[1][0] = z4; O[1][1] = z4;
  vf4 Lacc[2];
  Lacc[0] = z4; Lacc[1] = z4;

  vs4 ones4;
#pragma unroll
  for (int i = 0; i < 4; ++i) ones4[i] = (short)0x3F80;   // bf16 1.0

  const int ks_off = l15 * 40 + quad * 8;        // + tj*640
  const int vt_off = l15 * 72 + quad * 4;        // + tj2*1152 + tj*16

#define FA_TILE(T, CUR)                                                        \
  do {                                                                         \
    __syncthreads(); /* buf[CUR] (written last iter) visible */                \
    /* bias for ti=1 frags of this tile -- issued FIRST so its waitcnt */      \
    /* leaves the next-tile K/V loads in flight */                             \
    vf4 b1cur[4];                                                              \
    vi4 bpk1[2];                                                               \
    if (BF32) {                                                                \
      _Pragma("unroll")                                                        \
      for (int i = 0; i < 4; ++i)                                              \
        b1cur[i] = *(const vf4*)&Bf[((T) * 8 + 4 + i) * 1024];                 \
    } else {                                                                   \
      bpk1[0] = *(const vi4*)(Bpk + (T) * 4096 + 2048);                        \
      bpk1[1] = *(const vi4*)(Bpk + (T) * 4096 + 3072);                        \
    }                                                                          \
    if ((T) < 15) {                                                            \
      kreg = *(const vi4*)(Kg + ((T) + 1) * 2048);                             \
      vreg = *(const vi4*)(Vg + ((T) + 1) * 64);                               \
    }                                                                          \
    __builtin_amdgcn_s_setprio(1);                                             \
    _Pragma("unroll")                                                          \
    for (int tj = 0; tj < 4; ++tj) {                                           \
      vs8 bk = *(const vs8*)&Ks[CUR][tj * 640 + ks_off];                       \
      vs4 va0 = *(const vs4*)&Vt[CUR][vt_off + tj * 16];                       \
      vs4 va1 = *(const vs4*)&Vt[CUR][vt_off + 1152 + tj * 16];                \
      _Pragma("unroll")                                                        \
      for (int ti = 0; ti < 2; ++ti) {                                         \
        vf4 c = BF32 ? (ti ? b1cur[tj] : b0pre[tj])                            \
                     : unpack_bias((const u32*)(ti ? bpk1 : bpk_pre), tj);     \
        vf4 st = __builtin_amdgcn_mfma_f32_16x16x32_bf16(bk, af[ti], c,        \
                                                         0, 0, 0);             \
        float p0 = exp2_raw(st[0]);                                            \
        float p1 = exp2_raw(st[1]);                                            \
        float p2 = exp2_raw(st[2]);                                            \
        float p3 = exp2_raw(st[3]);                                            \
        vu2 pw; pw[0] = packbf_perm(p0, p1); pw[1] = packbf_perm(p2, p3);      \
        vs4 pf = __builtin_bit_cast(vs4, pw);                                  \
        O[ti][0] = __builtin_amdgcn_mfma_f32_16x16x16bf16_1k(va0, pf,          \
                                                             O[ti][0], 0, 0, 0); \
        O[ti][1] = __builtin_amdgcn_mfma_f32_16x16x16bf16_1k(va1, pf,          \
                                                             O[ti][1], 0, 0, 0); \
        Lacc[ti] = __builtin_amdgcn_mfma_f32_16x16x16bf16_1k(ones4, pf,        \
                                                             Lacc[ti], 0, 0, 0); \
      }                                                                        \
    }                                                                          \
    __builtin_amdgcn_s_setprio(0);                                             \
    /* stage next tile into the other LDS buffer; roll ti=0 bias prefetch */   \
    if ((T) < 15) {                                                            \
      *(vi4*)&Ks[(CUR) ^ 1][kv_j * 40 + kv_seg] = kreg;                        \
      *(vi4*)&Vt[(CUR) ^ 1][v_d * 72 + v_seg] = vreg;                          \
      if (BF32) {                                                              \
        _Pragma("unroll")                                                      \
        for (int i = 0; i < 4; ++i)                                            \
          b0pre[i] = *(const vf4*)&Bf[(((T) + 1) * 8 + i) * 1024];             \
      } else {                                                                 \
        bpk_pre[0] = *(const vi4*)(Bpk + ((T) + 1) * 4096);                    \
        bpk_pre[1] = *(const vi4*)(Bpk + ((T) + 1) * 4096 + 1024);             \
      }                                                                        \
    }                                                                          \
  } while (0)

  for (int tt = 0; tt < 16; tt += 2) {
    FA_TILE(tt, 0);
    FA_TILE(tt + 1, 1);
  }
#undef FA_TILE

  // epilogue
#pragma unroll
  for (int ti = 0; ti < 2; ++ti) {
    float inv = __builtin_amdgcn_rcpf(Lacc[ti][0]);
    int m = q0 + wave * 32 + ti * 16 + l15;
    int rowbase = (b * 1024 + m) * 256 + h * 32;
#pragma unroll
    for (int tj2 = 0; tj2 < 2; ++tj2) {
      u32 lo = (u32)f2bf(O[ti][tj2][0] * inv) | ((u32)f2bf(O[ti][tj2][1] * inv) << 16);
      u32 hi = (u32)f2bf(O[ti][tj2][2] * inv) | ((u32)f2bf(O[ti][tj2][3] * inv) << 16);
      vu2 pk; pk[0] = lo; pk[1] = hi;
      *(vu2*)&Ows[rowbase + tj2 * 16 + quad * 4] = pk;
    }
  }
}

// ---------------- launch ----------------
extern "C" void kernel_launch(void* const* d_in, const int* in_sizes, int n_in,
                              void* d_out, int out_size, void* d_ws, size_t ws_size,
                              hipStream_t stream) {
  (void)in_sizes; (void)n_in; (void)out_size;
  const float* x     = (const float*)d_in[0];
  const float* Wqkv  = (const float*)d_in[1];
  const float* table = (const float*)d_in[2];
  const float* Wout  = (const float*)d_in[3];
  const float* bout  = (const float*)d_in[4];
  const int*   rel   = (const int*)d_in[5];
  float* out = (float*)d_out;

  // Packed bf16 bias (s-major full-line layout): halves the bias stream vs fp32
  // and keeps prep stores / flash loads fully coalesced.
  const int use_f32 = 0;
  const size_t bias_bytes = 16777216ull;

  char* ws = (char*)d_ws;
  u16* xbf    = (u16*)(ws);              // bf16 x; later reused as attention O
  u16* Qws    = (u16*)(ws + 16777216);
  u16* Kws    = (u16*)(ws + 33554432);
  u16* Vtws   = (u16*)(ws + 50331648);   // [32][8][32][1024] V^T
  void* biasp = (void*)(ws + 67108864);
  u16* WqkvT  = (u16*)(ws + 67108864 + bias_bytes);
  u16* WoutT  = WqkvT + 196608;

  prep_all<<<5632, 256, 0, stream>>>(x, xbf, Wqkv, WqkvT, Wout, WoutT,
                                     rel, table, (u32*)biasp, (float*)biasp,
                                     use_f32);
  gemm_k256<0><<<1536, 256, 0, stream>>>(xbf, WqkvT, Qws, Kws, Vtws,
                                         nullptr, nullptr);
  flash_attn<0><<<2048, 256, 0, stream>>>(Qws, Kws, Vtws, biasp, xbf);
  gemm_k256<1><<<512, 256, 0, stream>>>(xbf, WoutT,
                                        nullptr, nullptr, nullptr, out, bout);
}